// Round 8
// baseline (345.488 us; speedup 1.0000x reference)
//
#include <hip/hip_runtime.h>

#define B_ 4
#define T_ 4096
#define C_ 2048
#define HD_ 128
#define M_ (B_*T_)   // 16384 rows total

typedef __bf16 bf8 __attribute__((ext_vector_type(8)));
typedef __bf16 bf16x2 __attribute__((ext_vector_type(2)));
typedef __bf16 bf16x4 __attribute__((ext_vector_type(4)));
typedef unsigned short u16x8 __attribute__((ext_vector_type(8)));
typedef unsigned short u16x4 __attribute__((ext_vector_type(4)));
typedef float f32x4 __attribute__((ext_vector_type(4)));

typedef __attribute__((address_space(3))) unsigned char lds_u8_t;
typedef __attribute__((address_space(1))) const unsigned char gm_u8_t;

// async global->LDS, 16B per lane; LDS dest = wave-uniform base + lane*16
__device__ __forceinline__ void glds16(const void* g, void* l) {
    __builtin_amdgcn_global_load_lds((gm_u8_t*)g, (lds_u8_t*)l, 16, 0, 0);
}

// counted waits (T4) — used in attn_part only (2-phase GEMM proven insensitive)
#define VMWAIT(N) do { asm volatile("s_waitcnt vmcnt(" #N ")" ::: "memory"); \
                       __builtin_amdgcn_sched_barrier(0); } while (0)
__device__ __forceinline__ void barrier_raw() {
    __builtin_amdgcn_sched_barrier(0);
    __builtin_amdgcn_s_barrier();
    __builtin_amdgcn_sched_barrier(0);
}

// hardware bf16 conversion (gfx950: v_cvt_pk_bf16_f32), RNE
__device__ __forceinline__ bf8 cvt_bf8(float4 a, float4 b) {
    bf8 t;
    t[0]=(__bf16)a.x; t[1]=(__bf16)a.y; t[2]=(__bf16)a.z; t[3]=(__bf16)a.w;
    t[4]=(__bf16)b.x; t[5]=(__bf16)b.y; t[6]=(__bf16)b.z; t[7]=(__bf16)b.w;
    return t;
}
__device__ __forceinline__ unsigned pk2(float a, float b) {
    bf16x2 t; t[0] = (__bf16)a; t[1] = (__bf16)b;
    return __builtin_bit_cast(unsigned, t);
}
__device__ __forceinline__ u16x4 pk4(float a, float b, float c, float d) {
    bf16x4 t; t[0]=(__bf16)a; t[1]=(__bf16)b; t[2]=(__bf16)c; t[3]=(__bf16)d;
    return __builtin_bit_cast(u16x4, t);
}
__device__ __forceinline__ bf8 ld_bf8(const unsigned short* p) {
    u16x8 t = *(const u16x8*)p;
    return __builtin_bit_cast(bf8, t);
}
__device__ __forceinline__ float bf2f(unsigned short h) {
    unsigned u = ((unsigned)h) << 16;
    return __builtin_bit_cast(float, u);
}
__device__ __forceinline__ f32x4 zero4() { f32x4 v = {0.f,0.f,0.f,0.f}; return v; }

// ---------------------------------------------------------------------------
// Kernel 0: convert Wq|Wk|Wv (fp32) -> wbf (bf16), contiguous [3][128][2048]
// ---------------------------------------------------------------------------
__global__ __launch_bounds__(256) void wconv(
    const float* __restrict__ Wq, const float* __restrict__ Wk,
    const float* __restrict__ Wv, unsigned short* __restrict__ wbf)
{
    int idx = blockIdx.x * 256 + threadIdx.x;   // 0..98303
    int e = idx * 8;
    int z = e >> 18;                            // 128*2048 = 262144 = 2^18
    int r = e & 262143;
    const float* src = (z == 0 ? Wq : z == 1 ? Wk : Wv) + r;
    float4 a = *(const float4*)src;
    float4 b = *(const float4*)(src + 4);
    bf8 o = cvt_bf8(a, b);
    *(u16x8*)(wbf + e) = __builtin_bit_cast(u16x8, o);
}

// ---------------------------------------------------------------------------
// Kernel 1 (r8): m230-correspondence GEMM. Six schedule variants all pinned
// at ~90 us / MfmaUtil 11%; the reference 2-phase (m230-V0: 256^2, 8 waves,
// 64 MFMA/wave/step, 1 blk/CU, plain drains) is 682 TF => the knob is
// PER-BARRIER COMPUTE, not load/barrier plumbing. This version: per-z
// BM=256 x BN=128, 512 threads (8 waves, 4M x 2N), wave-tile 64x64
// (acc 4x4), 32 MFMA/wave/K-step, 256 MFMA/block-barrier (4x r7).
// LDS 96 KB dbuf, 1 block/CU. x REG-staged (f32->cvt->swizzled ds_write,
// T14 order: load(t+1) -> compute(t) -> write(t+1) -> barrier). W via
// glds16 (bf16 from wbf). Plain __syncthreads (T4 proven irrelevant at
// 2-phase). Grid 192 (75% CU use, factored into the prediction).
// ---------------------------------------------------------------------------
__global__ __launch_bounds__(512, 2) void qkv_gemm(
    const float* __restrict__ x, const unsigned short* __restrict__ wbf,
    const float* __restrict__ cosp, const float* __restrict__ sinp,
    unsigned short* __restrict__ qws, unsigned short* __restrict__ kws,
    unsigned short* __restrict__ vws)
{
    __shared__ __align__(16) unsigned short xsb[2][256*64]; // 2 x 32 KB bf16
    __shared__ __align__(16) unsigned short wsb[2][128*64]; // 2 x 16 KB bf16

    const int tid = threadIdx.x;
    const int w = tid >> 6, l = tid & 63;    // 8 waves
    // decode: u = s*8+xcd spreads each ct-group over all XCDs
    const int id = blockIdx.x;               // 0..191
    const int xcd = id & 7;
    const int u = (id >> 3) * 8 + xcd;       // 0..191
    const int ct = u >> 6;                   // 0=q,1=k,2=v (64 blocks each)
    const int rt = u & 63;                   // row-tile 0..63
    const int rowbase = rt * 256;
    const unsigned short* wsrc = wbf + (size_t)ct * (HD_ * C_);

    const int swz = l & 7;
    const int aq  = l >> 4;
    const int coll = l & 15;
    const int wm = w >> 1;                   // 0..3: 64-row quad
    const int wn = w & 1;                    // 0..1: 64-col half

    // x staging decode: thread -> (row 0..255, 32-float half 0..1)
    const int xrow = tid >> 1;
    const int xseg = tid & 1;

    f32x4 acc[4][4];
    #pragma unroll
    for (int i = 0; i < 4; ++i)
        #pragma unroll
        for (int j = 0; j < 4; ++j) acc[i][j] = zero4();

    // W staging (glds16): 128 rows x 64 bf16 = 16 calls, 2 per wave
    auto stageW = [&](int kc, int bi) {
        #pragma unroll
        for (int c = 0; c < 2; ++c) {
            int row = w * 16 + c * 8 + (l >> 3);
            int fb = (l & 7) ^ (row & 7);
            glds16(wsrc + (size_t)row * C_ + kc + fb * 8,
                   (void*)&wsb[bi][(w * 16 + c * 8) * 64]);
        }
    };
    // x: issue global f32 loads for slab kc into named reg set (8 float4)
    auto loadX = [&](int kc, float4* xf) {
        const float* gp = x + (size_t)(rowbase + xrow) * C_ + kc + xseg * 32;
        #pragma unroll
        for (int j = 0; j < 8; ++j) xf[j] = ((const float4*)gp)[j];
    };
    // x: cvt reg set -> bf16, swizzled ds_write into buffer bi
    auto writeX = [&](const float4* xf, int bi) {
        #pragma unroll
        for (int j = 0; j < 4; ++j) {
            int cb = (xseg * 4 + j) ^ (xrow & 7);      // 8-bf16 chunk, swizzled
            bf8 v = cvt_bf8(xf[j * 2], xf[j * 2 + 1]);
            *(u16x8*)&xsb[bi][xrow * 64 + cb * 8] = __builtin_bit_cast(u16x8, v);
        }
    };
    // compute one K-slab: 2 k-subs x 16 MFMA (4x4 acc) = 32 MFMA/wave
    auto compute = [&](int bi) {
        #pragma unroll
        for (int ks_ = 0; ks_ < 2; ++ks_) {
            const int slot8 = ((ks_ * 4 + aq) ^ swz) << 3;
            bf8 a[4], b[4];
            #pragma unroll
            for (int mi = 0; mi < 4; ++mi)
                a[mi] = ld_bf8(&xsb[bi][(wm * 64 + mi * 16 + coll) * 64 + slot8]);
            #pragma unroll
            for (int nt = 0; nt < 4; ++nt)
                b[nt] = ld_bf8(&wsb[bi][(wn * 64 + nt * 16 + coll) * 64 + slot8]);
            #pragma unroll
            for (int mi = 0; mi < 4; ++mi)
                #pragma unroll
                for (int nt = 0; nt < 4; ++nt)
                    acc[mi][nt] = __builtin_amdgcn_mfma_f32_16x16x32_bf16(a[mi], b[nt], acc[mi][nt], 0, 0, 0);
        }
    };

    float4 xA[8], xB[8];
    // prologue: slab0 fully staged (one-time exposed latency)
    loadX(0, xA);
    stageW(0, 0);
    writeX(xA, 0);
    __syncthreads();                         // buf0 ready (drains glds16 too)

    // steady state: issue loads(t+1) early, compute(t), write(t+1), barrier.
    #pragma unroll 1
    for (int t = 0; t < 32; t += 2) {
        {
            if (t + 1 < 32) { loadX((t + 1) * 64, xB); stageW((t + 1) * 64, 1); }
            compute(0);
            if (t + 1 < 32) writeX(xB, 1);
            __syncthreads();
        }
        {
            if (t + 2 < 32) { loadX((t + 2) * 64, xA); stageW((t + 2) * 64, 0); }
            compute(1);
            if (t + 2 < 32) writeX(xA, 0);
            __syncthreads();
        }
    }

    // epilogue — z uniform per block (z == ct)
    const int rl0 = aq * 4;
    const int mrow = wm * 64;
    if (ct < 2) {
        const float QSC = 0.022097086912079608f * 1.44269504088896340736f;
        const float fs = (ct == 0) ? QSC : 1.0f;
        unsigned short* dst = (ct == 0) ? qws : kws;
        #pragma unroll
        for (int mi = 0; mi < 4; ++mi) {
            #pragma unroll
            for (int nt = 0; nt < 4; ++nt) {
                int col = wn * 64 + nt * 16 + coll;        // 0..127 within z
                #pragma unroll
                for (int r = 0; r < 4; ++r) {
                    float val = acc[mi][nt][r];
                    float oth = __shfl_xor(val, 1, 64);
                    int grow = rowbase + mrow + mi * 16 + rl0 + r;
                    int t = grow & (T_ - 1);
                    if ((coll & 1) == 0) {
                        int i = col >> 1;
                        float cv = cosp[t * 64 + i], sv = sinp[t * 64 + i];
                        float o_r = (val * cv - oth * sv) * fs;
                        float o_i = (val * sv + oth * cv) * fs;
                        *(unsigned*)&dst[(size_t)grow * HD_ + col] = pk2(o_r, o_i);
                    }
                }
            }
        }
    } else {
        const int bq = rowbase >> 12;
        #pragma unroll
        for (int mi = 0; mi < 4; ++mi) {
            int tb = (rowbase + mrow + mi * 16 + rl0) & (T_ - 1);
            #pragma unroll
            for (int nt = 0; nt < 4; ++nt) {
                int col = wn * 64 + nt * 16 + coll;        // 0..127 within v
                u16x4 pk = pk4(acc[mi][nt][0], acc[mi][nt][1], acc[mi][nt][2], acc[mi][nt][3]);
                *(u16x4*)&vws[(size_t)(bq * HD_ + col) * T_ + tb] = pk;  // transposed
            }
        }
    }
}

// ---------------------------------------------------------------------------
// Kernel 2a (r7, unchanged): counted-vmcnt split-K causal flash attention.
// Grid 1152 = 4 b x 288 jobs (<=8 K-tiles, heavy-first, XCD-paired b).
// ---------------------------------------------------------------------------
__global__ __launch_bounds__(256) void attn_part(
    const unsigned short* __restrict__ qws, const unsigned short* __restrict__ kws,
    const unsigned short* __restrict__ vws,
    unsigned short* __restrict__ partO, float* __restrict__ partL)
{
    __shared__ __align__(16) unsigned short ks[2][64*128];   // 2 x 16 KB
    __shared__ __align__(16) unsigned short vs[2][128*64];   // 2 x 16 KB
    __shared__ __align__(16) unsigned short ps[4*16*72];     // 9 KB (per-wave P)

    const int tid = threadIdx.x;
    const int w = tid >> 6, l = tid & 63;
    const int id = blockIdx.x;
    const int xcd = id & 7;
    const int b = xcd >> 1;
    const int j = (id >> 3) * 2 + (xcd & 1);    // 0..287
    const int sp = 287 - j;
    int g = 0;
    while (4 * (g + 1) * (g + 2) <= sp) ++g;
    const int r_ = sp - 4 * g * (g + 1);
    const int qdiv = r_ / (g + 1);
    const int qt = 8 * g + qdiv;                // 0..63
    const int c  = r_ - qdiv * (g + 1);         // chunk 0..g
    const int ntiles = (c < g) ? 8 : ((qt & 7) + 1);
    const int slot = b * 288 + 4 * g * (g + 1) + (qt & 7) * (g + 1) + c;
    const int qbase = qt * 64;
    const int cbase = c * 512;
    const size_t rowoff = (size_t)b * T_;

    const int swz = l & 7, aq = l >> 4, coll = l & 15;
    unsigned short* psw = ps + w * (16 * 72);

    bf8 ones;
    #pragma unroll
    for (int e = 0; e < 8; ++e) ones[e] = (__bf16)1.0f;

    bf8 qf[4];
    {
        const unsigned short* qp = qws + (rowoff + qbase + w * 16 + coll) * HD_ + aq * 8;
        #pragma unroll
        for (int kk = 0; kk < 4; ++kk) qf[kk] = ld_bf8(qp + kk * 32);
    }

    f32x4 accO[8];
    #pragma unroll
    for (int i = 0; i < 8; ++i) accO[i] = zero4();
    f32x4 accL = zero4();

    auto stage = [&](int sbase, int bi) {
        #pragma unroll
        for (int cc = 0; cc < 4; ++cc) {              // K: 64 rows x 128
            int row = w * 16 + cc * 4 + aq;
            int fb = coll ^ (row & 7);
            glds16(kws + (rowoff + sbase + row) * HD_ + fb * 8,
                   (void*)&ks[bi][(w * 16 + cc * 4) * 128]);
        }
        #pragma unroll
        for (int cc = 0; cc < 4; ++cc) {              // V: 128 d-rows x 64 s
            int row = w * 32 + cc * 8 + (l >> 3);
            int fb = (l & 7) ^ (row & 7);
            glds16(vws + ((size_t)(b * HD_ + row)) * T_ + sbase + fb * 8,
                   (void*)&vs[bi][(w * 32 + cc * 8) * 64]);
        }
    };

    stage(cbase, 0);
    VMWAIT(0);
    barrier_raw();

    int cur = 0;
    for (int st = 0; st < ntiles; ++st) {
        const int sbase = cbase + st * 64;

        if (st + 1 < ntiles) {
            stage(cbase + (st + 1) * 64, cur ^ 1);    // +8, stays in flight
            VMWAIT(8);                                // certify stage(st)
        } else {
            VMWAIT(0);
        }
        barrier_raw();

        const bool masked = (sbase == qbase);

        f32x4 sacc[4];
        #pragma unroll
        for (int i = 0; i < 4; ++i) sacc[i] = zero4();
        #pragma unroll
        for (int kk = 0; kk < 4; ++kk) {
            const int slot8 = ((kk * 4 + aq) ^ swz) << 3;
            #pragma unroll
            for (int nt = 0; nt < 4; ++nt) {
                bf8 bb = ld_bf8(&ks[cur][(nt * 16 + coll) * 128 + slot8]);
                sacc[nt] = __builtin_amdgcn_mfma_f32_16x16x32_bf16(qf[kk], bb, sacc[nt], 0, 0, 0);
            }
        }

        #pragma unroll
        for (int r = 0; r < 4; ++r) {
            float s0 = sacc[0][r], s1 = sacc[1][r], s2 = sacc[2][r], s3 = sacc[3][r];
            if (masked) {
                int qi = qbase + w * 16 + aq * 4 + r;
                int ki = sbase + coll;
                s0 = (ki      > qi) ? -1e30f : s0;
                s1 = (ki + 16 > qi) ? -1e30f : s1;
                s2 = (ki + 32 > qi) ? -1e30f : s2;
                s3 = (ki + 48 > qi) ? -1e30f : s3;
            }
            float p0 = __builtin_amdgcn_exp2f(s0);
            float p1 = __builtin_amdgcn_exp2f(s1);
            float p2 = __builtin_amdgcn_exp2f(s2);
            float p3 = __builtin_amdgcn_exp2f(s3);
            const int prow = (aq * 4 + r) * 72;
            psw[prow + coll]      = __builtin_bit_cast(unsigned short, (__bf16)p0);
            psw[prow + 16 + coll] = __builtin_bit_cast(unsigned short, (__bf16)p1);
            psw[prow + 32 + coll] = __builtin_bit_cast(unsigned short, (__bf16)p2);
            psw[prow + 48 + coll] = __builtin_bit_cast(unsigned short, (__bf16)p3);
        }

        #pragma unroll
        for (int kk = 0; kk < 2; ++kk) {
            bf8 a = ld_bf8(&psw[coll * 72 + kk * 32 + aq * 8]);
            accL = __builtin_amdgcn_mfma_f32_16x16x32_bf16(a, ones, accL, 0, 0, 0);
            const int slot8 = ((kk * 4 + aq) ^ swz) << 3;
            #pragma unroll
            for (int nt = 0; nt < 8; ++nt) {
                bf8 bb = ld_bf8(&vs[cur][(nt * 16 + coll) * 64 + slot8]);
                accO[nt] = __builtin_amdgcn_mfma_f32_16x16x32_bf16(a, bb, accO[nt], 0, 0, 0);
            }
        }

        barrier_raw();
        cur ^= 1;
    }

    unsigned short* op = partO + (size_t)slot * (64 * 128);
    #pragma unroll
    for (int r = 0; r < 4; ++r) {
        int row = w * 16 + aq * 4 + r;
        #pragma unroll
        for (int nt = 0; nt < 8; ++nt) {
            __bf16 ob = (__bf16)accO[nt][r];
            op[row * 128 + nt * 16 + coll] = __builtin_bit_cast(unsigned short, ob);
        }
        if (coll == 0) partL[slot * 64 + row] = accL[r];
    }
}

// ---------------------------------------------------------------------------
// Kernel 2b: merge partials. Grid 256 = (b,qt).
// ---------------------------------------------------------------------------
__global__ __launch_bounds__(256) void attn_merge(
    const unsigned short* __restrict__ partO, const float* __restrict__ partL,
    float* __restrict__ out)
{
    const int bq = blockIdx.x;
    const int b = bq >> 6, qt = bq & 63;
    const int g = qt >> 3;
    const int nc = g + 1;
    const int slotbase = b * 288 + 4 * g * (g + 1) + (qt & 7) * (g + 1);
    const int row = threadIdx.x >> 2;
    const int cg = (threadIdx.x & 3) * 32;

    float acc[32];
    #pragma unroll
    for (int e = 0; e < 32; ++e) acc[e] = 0.f;
    float L = 0.f;
    for (int c = 0; c < nc; ++c) {
        const int slot = slotbase + c;
        L += partL[slot * 64 + row];
        const unsigned short* op = partO + (size_t)slot * (64 * 128) + row * 128 + cg;
        #pragma unroll
        for (int k = 0; k < 4; ++k) {
            u16x8 t = *(const u16x8*)(op + k * 8);
            #pragma unroll
            for (int e = 0; e < 8; ++e) acc[k * 8 + e] += bf2f(t[e]);
        }
    }
    float inv = 1.f / L;
    float* dst = out + ((size_t)(b * T_ + qt * 64 + row)) * HD_ + cg;
    #pragma unroll
    for (int k = 0; k < 8; ++k) {
        float4 o;
        o.x = acc[k * 4 + 0] * inv; o.y = acc[k * 4 + 1] * inv;
        o.z = acc[k * 4 + 2] * inv; o.w = acc[k * 4 + 3] * inv;
        *(float4*)(dst + k * 4) = o;
    }
}

extern "C" void kernel_launch(void* const* d_in, const int* in_sizes, int n_in,
                              void* d_out, int out_size, void* d_ws, size_t ws_size,
                              hipStream_t stream) {
    const float* x    = (const float*)d_in[0];
    const float* Wq   = (const float*)d_in[1];
    const float* Wk   = (const float*)d_in[2];
    const float* Wv   = (const float*)d_in[3];
    const float* cosp = (const float*)d_in[4];
    const float* sinp = (const float*)d_in[5];
    float* out = (float*)d_out;

    unsigned short* qws = (unsigned short*)d_ws;              // 4 MB
    unsigned short* kws = qws + (size_t)M_ * HD_;             // 4 MB
    unsigned short* vws = kws + (size_t)M_ * HD_;             // (B,128,T) 4 MB
    unsigned short* wbf = vws + (size_t)M_ * HD_;             // 1.5 MB
    unsigned short* partO = wbf + (size_t)3 * HD_ * C_;       // 1152*8192 u16 = 18.9 MB
    float* partL = (float*)(partO + (size_t)1152 * 64 * 128); // 1152*64 f32

    wconv<<<dim3(384), dim3(256), 0, stream>>>(Wq, Wk, Wv, wbf);
    qkv_gemm<<<dim3(192), dim3(512), 0, stream>>>(x, wbf, cosp, sinp, qws, kws, vws);
    attn_part<<<dim3(1152), dim3(256), 0, stream>>>(qws, kws, vws, partO, partL);
    attn_merge<<<dim3(256), dim3(256), 0, stream>>>(partO, partL, out);
}

// Round 10
// 307.136 us; speedup vs baseline: 1.1249x; 1.1249x over previous
//
#include <hip/hip_runtime.h>

#define B_ 4
#define T_ 4096
#define C_ 2048
#define HD_ 128
#define M_ (B_*T_)   // 16384 rows total

typedef __bf16 bf8 __attribute__((ext_vector_type(8)));
typedef __bf16 bf16x2 __attribute__((ext_vector_type(2)));
typedef __bf16 bf16x4 __attribute__((ext_vector_type(4)));
typedef unsigned short u16x8 __attribute__((ext_vector_type(8)));
typedef unsigned short u16x4 __attribute__((ext_vector_type(4)));
typedef float f32x4 __attribute__((ext_vector_type(4)));

typedef __attribute__((address_space(3))) unsigned char lds_u8_t;
typedef __attribute__((address_space(1))) const unsigned char gm_u8_t;

// async global->LDS, 16B per lane; LDS dest = wave-uniform base + lane*16
__device__ __forceinline__ void glds16(const void* g, void* l) {
    __builtin_amdgcn_global_load_lds((gm_u8_t*)g, (lds_u8_t*)l, 16, 0, 0);
}

// counted waits (T4) — attn_part only
#define VMWAIT(N) do { asm volatile("s_waitcnt vmcnt(" #N ")" ::: "memory"); \
                       __builtin_amdgcn_sched_barrier(0); } while (0)
__device__ __forceinline__ void barrier_raw() {
    __builtin_amdgcn_sched_barrier(0);
    __builtin_amdgcn_s_barrier();
    __builtin_amdgcn_sched_barrier(0);
}

// hardware bf16 conversion (gfx950: v_cvt_pk_bf16_f32), RNE
__device__ __forceinline__ bf8 cvt_bf8(float4 a, float4 b) {
    bf8 t;
    t[0]=(__bf16)a.x; t[1]=(__bf16)a.y; t[2]=(__bf16)a.z; t[3]=(__bf16)a.w;
    t[4]=(__bf16)b.x; t[5]=(__bf16)b.y; t[6]=(__bf16)b.z; t[7]=(__bf16)b.w;
    return t;
}
__device__ __forceinline__ unsigned pk2(float a, float b) {
    bf16x2 t; t[0] = (__bf16)a; t[1] = (__bf16)b;
    return __builtin_bit_cast(unsigned, t);
}
__device__ __forceinline__ u16x4 pk4(float a, float b, float c, float d) {
    bf16x4 t; t[0]=(__bf16)a; t[1]=(__bf16)b; t[2]=(__bf16)c; t[3]=(__bf16)d;
    return __builtin_bit_cast(u16x4, t);
}
__device__ __forceinline__ bf8 ld_bf8(const unsigned short* p) {
    u16x8 t = *(const u16x8*)p;
    return __builtin_bit_cast(bf8, t);
}
__device__ __forceinline__ float bf2f(unsigned short h) {
    unsigned u = ((unsigned)h) << 16;
    return __builtin_bit_cast(float, u);
}
__device__ __forceinline__ f32x4 zero4() { f32x4 v = {0.f,0.f,0.f,0.f}; return v; }

// ---------------------------------------------------------------------------
// Kernel 0: convert Wq|Wk|Wv (fp32) -> wbf (bf16), contiguous [3][128][2048]
// ---------------------------------------------------------------------------
__global__ __launch_bounds__(256) void wconv(
    const float* __restrict__ Wq, const float* __restrict__ Wk,
    const float* __restrict__ Wv, unsigned short* __restrict__ wbf)
{
    int idx = blockIdx.x * 256 + threadIdx.x;   // 0..98303
    int e = idx * 8;
    int z = e >> 18;                            // 128*2048 = 262144 = 2^18
    int r = e & 262143;
    const float* src = (z == 0 ? Wq : z == 1 ? Wk : Wv) + r;
    float4 a = *(const float4*)src;
    float4 b = *(const float4*)(src + 4);
    bf8 o = cvt_bf8(a, b);
    *(u16x8*)(wbf + e) = __builtin_bit_cast(u16x8, o);
}

// ---------------------------------------------------------------------------
// Kernel 1 (r9 resubmitted verbatim — unmeasured due to infra): TLP-max GEMM.
// Evidence across 7 variants: time per staged byte per CU is monotone in
// blocks/CU (3blk=29 ns/KB, 1.5blk=41, 1blk=58) with NO pipe saturated and
// warm-L3 invariance => latency-bound with insufficient memory-level
// parallelism; co-resident blocks are the only proven concurrency source.
// BM=32, BN=128 per-z -> grid 1536 = 6 blocks/CU. Single-buffered 20 KB LDS,
// r2's proven 2-barrier schedule, 4 waves of 16x64 wave-tiles (acc 1x4),
// x reg-staged f32->bf16 (1 cvt + 1 ds_write per thread/iter), W via glds16.
// Falsifier: if time tracks bytes (>=110 us) the TLP theory is dead.
// ---------------------------------------------------------------------------
__global__ __launch_bounds__(256, 6) void qkv_gemm(
    const float* __restrict__ x, const unsigned short* __restrict__ wbf,
    const float* __restrict__ cosp, const float* __restrict__ sinp,
    unsigned short* __restrict__ qws, unsigned short* __restrict__ kws,
    unsigned short* __restrict__ vws)
{
    __shared__ __align__(16) unsigned short xsb[32*64];   // 4 KB bf16
    __shared__ __align__(16) unsigned short wsb[128*64];  // 16 KB bf16

    const int tid = threadIdx.x;
    const int w = tid >> 6, l = tid & 63;
    // decode: XCD-chunked; 512 row-tiles of 32 rows x 3 z
    const int bid = blockIdx.x;              // 0..1535
    const int xcd = bid & 7;
    const int s = bid >> 3;                  // 0..191
    const int ct = s % 3;                    // 0=q,1=k,2=v (uniform per block)
    const int mm = s / 3;                    // 0..63
    const int rowbase = (mm * 8 + xcd) * 32;
    const unsigned short* wsrc = wbf + (size_t)ct * (HD_ * C_);

    const int swz = l & 7;
    const int aq  = l >> 4;
    const int coll = l & 15;
    const int wm = w & 1;                    // 16-row half
    const int wn = w >> 1;                   // 64-col half

    // x staging decode: thread -> (row 0..31, 8-f32 segment 0..7)
    const int xrow = tid >> 3;
    const int xseg = tid & 7;
    const int xcb  = xseg ^ (xrow & 7);      // swizzled 8-bf16 chunk slot

    f32x4 acc[4];
    #pragma unroll
    for (int j = 0; j < 4; ++j) acc[j] = zero4();

    const float* xg = x + (size_t)(rowbase + xrow) * C_ + xseg * 8;

    for (int kc = 0; kc < C_; kc += 64) {
        __syncthreads();                     // prior compute's LDS reads done
        // W: 128 rows x 64 bf16, 4 glds16 per wave
        #pragma unroll
        for (int c = 0; c < 4; ++c) {
            int row = w * 32 + c * 8 + (l >> 3);
            int fb = (l & 7) ^ (row & 7);
            glds16(wsrc + (size_t)row * C_ + kc + fb * 8,
                   (void*)&wsb[(w * 32 + c * 8) * 64]);
        }
        // x: 32 rows x 64 f32, reg load -> cvt -> swizzled ds_write
        {
            float4 fa = *(const float4*)(xg + kc);
            float4 fb2 = *(const float4*)(xg + kc + 4);
            bf8 v = cvt_bf8(fa, fb2);
            *(u16x8*)&xsb[xrow * 64 + xcb * 8] = __builtin_bit_cast(u16x8, v);
        }
        __syncthreads();                     // staging visible (vmcnt0+lgkm0)

        // compute: 2 k-subs x (1 A-frag x 4 B-frags) = 8 MFMA/wave
        #pragma unroll
        for (int ks_ = 0; ks_ < 2; ++ks_) {
            const int slot8 = ((ks_ * 4 + aq) ^ swz) << 3;
            bf8 a = ld_bf8(&xsb[(wm * 16 + coll) * 64 + slot8]);
            #pragma unroll
            for (int nt = 0; nt < 4; ++nt) {
                bf8 bb = ld_bf8(&wsb[(wn * 64 + nt * 16 + coll) * 64 + slot8]);
                acc[nt] = __builtin_amdgcn_mfma_f32_16x16x32_bf16(a, bb, acc[nt], 0, 0, 0);
            }
        }
    }

    // epilogue — z uniform per block (z == ct); wave rows = rowbase + wm*16 + aq*4 + r
    if (ct < 2) {
        const float QSC = 0.022097086912079608f * 1.44269504088896340736f;
        const float fs = (ct == 0) ? QSC : 1.0f;
        unsigned short* dst = (ct == 0) ? qws : kws;
        #pragma unroll
        for (int nt = 0; nt < 4; ++nt) {
            int col = wn * 64 + nt * 16 + coll;            // 0..127 within z
            #pragma unroll
            for (int r = 0; r < 4; ++r) {
                float val = acc[nt][r];
                float oth = __shfl_xor(val, 1, 64);
                int grow = rowbase + wm * 16 + aq * 4 + r;
                int t = grow & (T_ - 1);
                if ((coll & 1) == 0) {
                    int i = col >> 1;
                    float cv = cosp[t * 64 + i], sv = sinp[t * 64 + i];
                    float o_r = (val * cv - oth * sv) * fs;
                    float o_i = (val * sv + oth * cv) * fs;
                    *(unsigned*)&dst[(size_t)grow * HD_ + col] = pk2(o_r, o_i);
                }
            }
        }
    } else {
        const int bq = rowbase >> 12;
        int tb = (rowbase + wm * 16 + aq * 4) & (T_ - 1);
        #pragma unroll
        for (int nt = 0; nt < 4; ++nt) {
            int col = wn * 64 + nt * 16 + coll;            // 0..127 within v
            u16x4 pk = pk4(acc[nt][0], acc[nt][1], acc[nt][2], acc[nt][3]);
            *(u16x4*)&vws[(size_t)(bq * HD_ + col) * T_ + tb] = pk;  // transposed
        }
    }
}

// ---------------------------------------------------------------------------
// Kernel 2a (r7, unchanged): counted-vmcnt split-K causal flash attention.
// Grid 1152 = 4 b x 288 jobs (<=8 K-tiles, heavy-first, XCD-paired b).
// ---------------------------------------------------------------------------
__global__ __launch_bounds__(256) void attn_part(
    const unsigned short* __restrict__ qws, const unsigned short* __restrict__ kws,
    const unsigned short* __restrict__ vws,
    unsigned short* __restrict__ partO, float* __restrict__ partL)
{
    __shared__ __align__(16) unsigned short ks[2][64*128];   // 2 x 16 KB
    __shared__ __align__(16) unsigned short vs[2][128*64];   // 2 x 16 KB
    __shared__ __align__(16) unsigned short ps[4*16*72];     // 9 KB (per-wave P)

    const int tid = threadIdx.x;
    const int w = tid >> 6, l = tid & 63;
    const int id = blockIdx.x;
    const int xcd = id & 7;
    const int b = xcd >> 1;
    const int j = (id >> 3) * 2 + (xcd & 1);    // 0..287
    const int sp = 287 - j;
    int g = 0;
    while (4 * (g + 1) * (g + 2) <= sp) ++g;
    const int r_ = sp - 4 * g * (g + 1);
    const int qdiv = r_ / (g + 1);
    const int qt = 8 * g + qdiv;                // 0..63
    const int c  = r_ - qdiv * (g + 1);         // chunk 0..g
    const int ntiles = (c < g) ? 8 : ((qt & 7) + 1);
    const int slot = b * 288 + 4 * g * (g + 1) + (qt & 7) * (g + 1) + c;
    const int qbase = qt * 64;
    const int cbase = c * 512;
    const size_t rowoff = (size_t)b * T_;

    const int swz = l & 7, aq = l >> 4, coll = l & 15;
    unsigned short* psw = ps + w * (16 * 72);

    bf8 ones;
    #pragma unroll
    for (int e = 0; e < 8; ++e) ones[e] = (__bf16)1.0f;

    bf8 qf[4];
    {
        const unsigned short* qp = qws + (rowoff + qbase + w * 16 + coll) * HD_ + aq * 8;
        #pragma unroll
        for (int kk = 0; kk < 4; ++kk) qf[kk] = ld_bf8(qp + kk * 32);
    }

    f32x4 accO[8];
    #pragma unroll
    for (int i = 0; i < 8; ++i) accO[i] = zero4();
    f32x4 accL = zero4();

    auto stage = [&](int sbase, int bi) {
        #pragma unroll
        for (int cc = 0; cc < 4; ++cc) {              // K: 64 rows x 128
            int row = w * 16 + cc * 4 + aq;
            int fb = coll ^ (row & 7);
            glds16(kws + (rowoff + sbase + row) * HD_ + fb * 8,
                   (void*)&ks[bi][(w * 16 + cc * 4) * 128]);
        }
        #pragma unroll
        for (int cc = 0; cc < 4; ++cc) {              // V: 128 d-rows x 64 s
            int row = w * 32 + cc * 8 + (l >> 3);
            int fb = (l & 7) ^ (row & 7);
            glds16(vws + ((size_t)(b * HD_ + row)) * T_ + sbase + fb * 8,
                   (void*)&vs[bi][(w * 32 + cc * 8) * 64]);
        }
    };

    stage(cbase, 0);
    VMWAIT(0);
    barrier_raw();

    int cur = 0;
    for (int st = 0; st < ntiles; ++st) {
        const int sbase = cbase + st * 64;

        if (st + 1 < ntiles) {
            stage(cbase + (st + 1) * 64, cur ^ 1);    // +8, stays in flight
            VMWAIT(8);                                // certify stage(st)
        } else {
            VMWAIT(0);
        }
        barrier_raw();

        const bool masked = (sbase == qbase);

        f32x4 sacc[4];
        #pragma unroll
        for (int i = 0; i < 4; ++i) sacc[i] = zero4();
        #pragma unroll
        for (int kk = 0; kk < 4; ++kk) {
            const int slot8 = ((kk * 4 + aq) ^ swz) << 3;
            #pragma unroll
            for (int nt = 0; nt < 4; ++nt) {
                bf8 bb = ld_bf8(&ks[cur][(nt * 16 + coll) * 128 + slot8]);
                sacc[nt] = __builtin_amdgcn_mfma_f32_16x16x32_bf16(qf[kk], bb, sacc[nt], 0, 0, 0);
            }
        }

        #pragma unroll
        for (int r = 0; r < 4; ++r) {
            float s0 = sacc[0][r], s1 = sacc[1][r], s2 = sacc[2][r], s3 = sacc[3][r];
            if (masked) {
                int qi = qbase + w * 16 + aq * 4 + r;
                int ki = sbase + coll;
                s0 = (ki      > qi) ? -1e30f : s0;
                s1 = (ki + 16 > qi) ? -1e30f : s1;
                s2 = (ki + 32 > qi) ? -1e30f : s2;
                s3 = (ki + 48 > qi) ? -1e30f : s3;
            }
            float p0 = __builtin_amdgcn_exp2f(s0);
            float p1 = __builtin_amdgcn_exp2f(s1);
            float p2 = __builtin_amdgcn_exp2f(s2);
            float p3 = __builtin_amdgcn_exp2f(s3);
            const int prow = (aq * 4 + r) * 72;
            psw[prow + coll]      = __builtin_bit_cast(unsigned short, (__bf16)p0);
            psw[prow + 16 + coll] = __builtin_bit_cast(unsigned short, (__bf16)p1);
            psw[prow + 32 + coll] = __builtin_bit_cast(unsigned short, (__bf16)p2);
            psw[prow + 48 + coll] = __builtin_bit_cast(unsigned short, (__bf16)p3);
        }

        #pragma unroll
        for (int kk = 0; kk < 2; ++kk) {
            bf8 a = ld_bf8(&psw[coll * 72 + kk * 32 + aq * 8]);
            accL = __builtin_amdgcn_mfma_f32_16x16x32_bf16(a, ones, accL, 0, 0, 0);
            const int slot8 = ((kk * 4 + aq) ^ swz) << 3;
            #pragma unroll
            for (int nt = 0; nt < 8; ++nt) {
                bf8 bb = ld_bf8(&vs[cur][(nt * 16 + coll) * 64 + slot8]);
                accO[nt] = __builtin_amdgcn_mfma_f32_16x16x32_bf16(a, bb, accO[nt], 0, 0, 0);
            }
        }

        barrier_raw();
        cur ^= 1;
    }

    unsigned short* op = partO + (size_t)slot * (64 * 128);
    #pragma unroll
    for (int r = 0; r < 4; ++r) {
        int row = w * 16 + aq * 4 + r;
        #pragma unroll
        for (int nt = 0; nt < 8; ++nt) {
            __bf16 ob = (__bf16)accO[nt][r];
            op[row * 128 + nt * 16 + coll] = __builtin_bit_cast(unsigned short, ob);
        }
        if (coll == 0) partL[slot * 64 + row] = accL[r];
    }
}

// ---------------------------------------------------------------------------
// Kernel 2b: merge partials. Grid 256 = (b,qt).
// ---------------------------------------------------------------------------
__global__ __launch_bounds__(256) void attn_merge(
    const unsigned short* __restrict__ partO, const float* __restrict__ partL,
    float* __restrict__ out)
{
    const int bq = blockIdx.x;
    const int b = bq >> 6, qt = bq & 63;
    const int g = qt >> 3;
    const int nc = g + 1;
    const int slotbase = b * 288 + 4 * g * (g + 1) + (qt & 7) * (g + 1);
    const int row = threadIdx.x >> 2;
    const int cg = (threadIdx.x & 3) * 32;

    float acc[32];
    #pragma unroll
    for (int e = 0; e < 32; ++e) acc[e] = 0.f;
    float L = 0.f;
    for (int c = 0; c < nc; ++c) {
        const int slot = slotbase + c;
        L += partL[slot * 64 + row];
        const unsigned short* op = partO + (size_t)slot * (64 * 128) + row * 128 + cg;
        #pragma unroll
        for (int k = 0; k < 4; ++k) {
            u16x8 t = *(const u16x8*)(op + k * 8);
            #pragma unroll
            for (int e = 0; e < 8; ++e) acc[k * 8 + e] += bf2f(t[e]);
        }
    }
    float inv = 1.f / L;
    float* dst = out + ((size_t)(b * T_ + qt * 64 + row)) * HD_ + cg;
    #pragma unroll
    for (int k = 0; k < 8; ++k) {
        float4 o;
        o.x = acc[k * 4 + 0] * inv; o.y = acc[k * 4 + 1] * inv;
        o.z = acc[k * 4 + 2] * inv; o.w = acc[k * 4 + 3] * inv;
        *(float4*)(dst + k * 4) = o;
    }
}

extern "C" void kernel_launch(void* const* d_in, const int* in_sizes, int n_in,
                              void* d_out, int out_size, void* d_ws, size_t ws_size,
                              hipStream_t stream) {
    const float* x    = (const float*)d_in[0];
    const float* Wq   = (const float*)d_in[1];
    const float* Wk   = (const float*)d_in[2];
    const float* Wv   = (const float*)d_in[3];
    const float* cosp = (const float*)d_in[4];
    const float* sinp = (const float*)d_in[5];
    float* out = (float*)d_out;

    unsigned short* qws = (unsigned short*)d_ws;              // 4 MB
    unsigned short* kws = qws + (size_t)M_ * HD_;             // 4 MB
    unsigned short* vws = kws + (size_t)M_ * HD_;             // (B,128,T) 4 MB
    unsigned short* wbf = vws + (size_t)M_ * HD_;             // 1.5 MB
    unsigned short* partO = wbf + (size_t)3 * HD_ * C_;       // 1152*8192 u16 = 18.9 MB
    float* partL = (float*)(partO + (size_t)1152 * 64 * 128); // 1152*64 f32

    wconv<<<dim3(384), dim3(256), 0, stream>>>(Wq, Wk, Wv, wbf);
    qkv_gemm<<<dim3(1536), dim3(256), 0, stream>>>(x, wbf, cosp, sinp, qws, kws, vws);
    attn_part<<<dim3(1152), dim3(256), 0, stream>>>(qws, kws, vws, partO, partL);
    attn_merge<<<dim3(256), dim3(256), 0, stream>>>(partO, partL, out);
}

// Round 12
// 297.926 us; speedup vs baseline: 1.1596x; 1.0309x over previous
//
#include <hip/hip_runtime.h>

#define B_ 4
#define T_ 4096
#define C_ 2048
#define HD_ 128
#define M_ (B_*T_)   // 16384 rows total

typedef __bf16 bf8 __attribute__((ext_vector_type(8)));
typedef __bf16 bf16x2 __attribute__((ext_vector_type(2)));
typedef __bf16 bf16x4 __attribute__((ext_vector_type(4)));
typedef unsigned short u16x8 __attribute__((ext_vector_type(8)));
typedef unsigned short u16x4 __attribute__((ext_vector_type(4)));
typedef float f32x4 __attribute__((ext_vector_type(4)));

typedef __attribute__((address_space(3))) unsigned char lds_u8_t;
typedef __attribute__((address_space(1))) const unsigned char gm_u8_t;

// async global->LDS, 16B per lane; LDS dest = wave-uniform base + lane*16
__device__ __forceinline__ void glds16(const void* g, void* l) {
    __builtin_amdgcn_global_load_lds((gm_u8_t*)g, (lds_u8_t*)l, 16, 0, 0);
}

// counted waits (T4) — attn_part only
#define VMWAIT(N) do { asm volatile("s_waitcnt vmcnt(" #N ")" ::: "memory"); \
                       __builtin_amdgcn_sched_barrier(0); } while (0)
__device__ __forceinline__ void barrier_raw() {
    __builtin_amdgcn_sched_barrier(0);
    __builtin_amdgcn_s_barrier();
    __builtin_amdgcn_sched_barrier(0);
}

// hardware bf16 conversion (gfx950: v_cvt_pk_bf16_f32), RNE
__device__ __forceinline__ bf8 cvt_bf8(float4 a, float4 b) {
    bf8 t;
    t[0]=(__bf16)a.x; t[1]=(__bf16)a.y; t[2]=(__bf16)a.z; t[3]=(__bf16)a.w;
    t[4]=(__bf16)b.x; t[5]=(__bf16)b.y; t[6]=(__bf16)b.z; t[7]=(__bf16)b.w;
    return t;
}
__device__ __forceinline__ unsigned pk2(float a, float b) {
    bf16x2 t; t[0] = (__bf16)a; t[1] = (__bf16)b;
    return __builtin_bit_cast(unsigned, t);
}
__device__ __forceinline__ u16x4 pk4(float a, float b, float c, float d) {
    bf16x4 t; t[0]=(__bf16)a; t[1]=(__bf16)b; t[2]=(__bf16)c; t[3]=(__bf16)d;
    return __builtin_bit_cast(u16x4, t);
}
__device__ __forceinline__ bf8 ld_bf8(const unsigned short* p) {
    u16x8 t = *(const u16x8*)p;
    return __builtin_bit_cast(bf8, t);
}
__device__ __forceinline__ float bf2f(unsigned short h) {
    unsigned u = ((unsigned)h) << 16;
    return __builtin_bit_cast(float, u);
}
__device__ __forceinline__ f32x4 zero4() { f32x4 v = {0.f,0.f,0.f,0.f}; return v; }

// ---------------------------------------------------------------------------
// Kernel 0: convert Wq|Wk|Wv (fp32) -> wbf (bf16), contiguous [3][128][2048]
// ---------------------------------------------------------------------------
__global__ __launch_bounds__(256) void wconv(
    const float* __restrict__ Wq, const float* __restrict__ Wk,
    const float* __restrict__ Wv, unsigned short* __restrict__ wbf)
{
    int idx = blockIdx.x * 256 + threadIdx.x;   // 0..98303
    int e = idx * 8;
    int z = e >> 18;                            // 128*2048 = 262144 = 2^18
    int r = e & 262143;
    const float* src = (z == 0 ? Wq : z == 1 ? Wk : Wv) + r;
    float4 a = *(const float4*)src;
    float4 b = *(const float4*)(src + 4);
    bf8 o = cvt_bf8(a, b);
    *(u16x8*)(wbf + e) = __builtin_bit_cast(u16x8, o);
}

// ---------------------------------------------------------------------------
// Kernel 1 (r11 resubmitted verbatim — unmeasured due to infra): BK=128,
// halve the iteration count. Law from 9 variants: per-BLOCK staging
// throughput constant ~10.5 GB/s (~2200-2600 cyc per K-step per block)
// regardless of bytes/schedule/vmcnt/source => fixed per-ITERATION
// serialization cost dominates. All variants ran 32 iters (BK=64); this
// runs 16 (BK=128) at constant blocks/CU (3) and constant staged bytes.
// Geometry: per-z BM=64, BK=128; LDS 48 KB single-buf; grid 768 = 3 blk/CU;
// 4 waves, wave-tile 32x64, acc 2x4; 32 MFMA/wave/iter; 16-slot XOR swizzle.
// Falsifier: qkv >= 80 us => cost is per-byte -> r12 folds x->bf16 into
// wconv (halves staged x bytes) instead of touching schedule again.
// ---------------------------------------------------------------------------
__global__ __launch_bounds__(256, 3) void qkv_gemm(
    const float* __restrict__ x, const unsigned short* __restrict__ wbf,
    const float* __restrict__ cosp, const float* __restrict__ sinp,
    unsigned short* __restrict__ qws, unsigned short* __restrict__ kws,
    unsigned short* __restrict__ vws)
{
    __shared__ __align__(16) unsigned short xsb[64*128];   // 16 KB bf16
    __shared__ __align__(16) unsigned short wsb[128*128];  // 32 KB bf16

    const int tid = threadIdx.x;
    const int w = tid >> 6, l = tid & 63;
    // decode: XCD-chunked; z-partners (same rowtile, z=0,1,2) share an XCD
    const int bid = blockIdx.x;              // 0..767
    const int xcd = bid & 7;
    const int s = bid >> 3;                  // 0..95
    const int ct = s % 3;                    // 0=q,1=k,2=v (uniform per block)
    const int mm = s / 3;                    // 0..31
    const int rowbase = (mm * 8 + xcd) * 64; // 256 row-tiles of 64
    const unsigned short* wsrc = wbf + (size_t)ct * (HD_ * C_);

    const int aq  = l >> 4;                  // 0..3
    const int coll = l & 15;
    const int wm = w & 1;                    // 32-row half
    const int wn = w >> 1;                   // 64-col half

    // x staging decode: thread -> (row 0..63, 32-f32 segment 0..3)
    const int xrow = tid >> 2;
    const int xseg = tid & 3;

    f32x4 acc[2][4];
    #pragma unroll
    for (int i = 0; i < 2; ++i)
        #pragma unroll
        for (int j = 0; j < 4; ++j) acc[i][j] = zero4();

    const float* xg = x + (size_t)(rowbase + xrow) * C_ + xseg * 32;

    for (int kc = 0; kc < C_; kc += 128) {   // 16 iterations
        __syncthreads();                     // prior compute's LDS reads done
        // W: 128 rows x 128 bf16 = 32 KB, 8 glds16/wave (4 rows x 16 lanes each)
        #pragma unroll
        for (int c = 0; c < 8; ++c) {
            int row = w * 32 + c * 4 + (l >> 4);
            int fb = coll ^ (row & 15);
            glds16(wsrc + (size_t)row * C_ + kc + fb * 8,
                   (void*)&wsb[(w * 32 + c * 4) * 128]);
        }
        // x: 64 rows x 128 f32 -> bf16; per thread 4 chunks of 8 f32
        #pragma unroll
        for (int j = 0; j < 4; ++j) {
            int ch = xseg * 4 + j;                     // 0..15
            float4 fa  = *(const float4*)(xg + kc + j * 8);
            float4 fb2 = *(const float4*)(xg + kc + j * 8 + 4);
            int slot = ch ^ (xrow & 15);
            bf8 v = cvt_bf8(fa, fb2);
            *(u16x8*)&xsb[xrow * 128 + slot * 8] = __builtin_bit_cast(u16x8, v);
        }
        __syncthreads();                     // staging visible (vmcnt0+lgkm0)

        // compute: 4 k-subs x (2 A x 4 B) = 32 MFMA/wave
        #pragma unroll
        for (int ks_ = 0; ks_ < 4; ++ks_) {
            const int kslot = ks_ * 4 + aq;            // 0..15
            bf8 a[2], b[4];
            #pragma unroll
            for (int mi = 0; mi < 2; ++mi) {
                int row = wm * 32 + mi * 16 + coll;    // row&15 == coll
                a[mi] = ld_bf8(&xsb[row * 128 + ((kslot ^ coll) << 3)]);
            }
            #pragma unroll
            for (int nt = 0; nt < 4; ++nt) {
                int row = wn * 64 + nt * 16 + coll;    // row&15 == coll
                b[nt] = ld_bf8(&wsb[row * 128 + ((kslot ^ coll) << 3)]);
            }
            #pragma unroll
            for (int mi = 0; mi < 2; ++mi)
                #pragma unroll
                for (int nt = 0; nt < 4; ++nt)
                    acc[mi][nt] = __builtin_amdgcn_mfma_f32_16x16x32_bf16(a[mi], b[nt], acc[mi][nt], 0, 0, 0);
        }
    }

    // epilogue — z uniform per block (z == ct)
    const int rl0 = aq * 4;
    const int mrow = wm * 32;
    if (ct < 2) {
        const float QSC = 0.022097086912079608f * 1.44269504088896340736f;
        const float fs = (ct == 0) ? QSC : 1.0f;
        unsigned short* dst = (ct == 0) ? qws : kws;
        #pragma unroll
        for (int mi = 0; mi < 2; ++mi) {
            #pragma unroll
            for (int nt = 0; nt < 4; ++nt) {
                int col = wn * 64 + nt * 16 + coll;        // 0..127 within z
                #pragma unroll
                for (int r = 0; r < 4; ++r) {
                    float val = acc[mi][nt][r];
                    float oth = __shfl_xor(val, 1, 64);
                    int grow = rowbase + mrow + mi * 16 + rl0 + r;
                    int t = grow & (T_ - 1);
                    if ((coll & 1) == 0) {
                        int i = col >> 1;
                        float cv = cosp[t * 64 + i], sv = sinp[t * 64 + i];
                        float o_r = (val * cv - oth * sv) * fs;
                        float o_i = (val * sv + oth * cv) * fs;
                        *(unsigned*)&dst[(size_t)grow * HD_ + col] = pk2(o_r, o_i);
                    }
                }
            }
        }
    } else {
        const int bq = rowbase >> 12;
        #pragma unroll
        for (int mi = 0; mi < 2; ++mi) {
            int tb = (rowbase + mrow + mi * 16 + rl0) & (T_ - 1);
            #pragma unroll
            for (int nt = 0; nt < 4; ++nt) {
                int col = wn * 64 + nt * 16 + coll;        // 0..127 within v
                u16x4 pk = pk4(acc[mi][nt][0], acc[mi][nt][1], acc[mi][nt][2], acc[mi][nt][3]);
                *(u16x4*)&vws[(size_t)(bq * HD_ + col) * T_ + tb] = pk;  // transposed
            }
        }
    }
}

// ---------------------------------------------------------------------------
// Kernel 2a (r7, unchanged): counted-vmcnt split-K causal flash attention.
// Grid 1152 = 4 b x 288 jobs (<=8 K-tiles, heavy-first, XCD-paired b).
// ---------------------------------------------------------------------------
__global__ __launch_bounds__(256) void attn_part(
    const unsigned short* __restrict__ qws, const unsigned short* __restrict__ kws,
    const unsigned short* __restrict__ vws,
    unsigned short* __restrict__ partO, float* __restrict__ partL)
{
    __shared__ __align__(16) unsigned short ks[2][64*128];   // 2 x 16 KB
    __shared__ __align__(16) unsigned short vs[2][128*64];   // 2 x 16 KB
    __shared__ __align__(16) unsigned short ps[4*16*72];     // 9 KB (per-wave P)

    const int tid = threadIdx.x;
    const int w = tid >> 6, l = tid & 63;
    const int id = blockIdx.x;
    const int xcd = id & 7;
    const int b = xcd >> 1;
    const int j = (id >> 3) * 2 + (xcd & 1);    // 0..287
    const int sp = 287 - j;
    int g = 0;
    while (4 * (g + 1) * (g + 2) <= sp) ++g;
    const int r_ = sp - 4 * g * (g + 1);
    const int qdiv = r_ / (g + 1);
    const int qt = 8 * g + qdiv;                // 0..63
    const int c  = r_ - qdiv * (g + 1);         // chunk 0..g
    const int ntiles = (c < g) ? 8 : ((qt & 7) + 1);
    const int slot = b * 288 + 4 * g * (g + 1) + (qt & 7) * (g + 1) + c;
    const int qbase = qt * 64;
    const int cbase = c * 512;
    const size_t rowoff = (size_t)b * T_;

    const int swz = l & 7, aq = l >> 4, coll = l & 15;
    unsigned short* psw = ps + w * (16 * 72);

    bf8 ones;
    #pragma unroll
    for (int e = 0; e < 8; ++e) ones[e] = (__bf16)1.0f;

    bf8 qf[4];
    {
        const unsigned short* qp = qws + (rowoff + qbase + w * 16 + coll) * HD_ + aq * 8;
        #pragma unroll
        for (int kk = 0; kk < 4; ++kk) qf[kk] = ld_bf8(qp + kk * 32);
    }

    f32x4 accO[8];
    #pragma unroll
    for (int i = 0; i < 8; ++i) accO[i] = zero4();
    f32x4 accL = zero4();

    auto stage = [&](int sbase, int bi) {
        #pragma unroll
        for (int cc = 0; cc < 4; ++cc) {              // K: 64 rows x 128
            int row = w * 16 + cc * 4 + aq;
            int fb = coll ^ (row & 7);
            glds16(kws + (rowoff + sbase + row) * HD_ + fb * 8,
                   (void*)&ks[bi][(w * 16 + cc * 4) * 128]);
        }
        #pragma unroll
        for (int cc = 0; cc < 4; ++cc) {              // V: 128 d-rows x 64 s
            int row = w * 32 + cc * 8 + (l >> 3);
            int fb = (l & 7) ^ (row & 7);
            glds16(vws + ((size_t)(b * HD_ + row)) * T_ + sbase + fb * 8,
                   (void*)&vs[bi][(w * 32 + cc * 8) * 64]);
        }
    };

    stage(cbase, 0);
    VMWAIT(0);
    barrier_raw();

    int cur = 0;
    for (int st = 0; st < ntiles; ++st) {
        const int sbase = cbase + st * 64;

        if (st + 1 < ntiles) {
            stage(cbase + (st + 1) * 64, cur ^ 1);    // +8, stays in flight
            VMWAIT(8);                                // certify stage(st)
        } else {
            VMWAIT(0);
        }
        barrier_raw();

        const bool masked = (sbase == qbase);

        f32x4 sacc[4];
        #pragma unroll
        for (int i = 0; i < 4; ++i) sacc[i] = zero4();
        #pragma unroll
        for (int kk = 0; kk < 4; ++kk) {
            const int slot8 = ((kk * 4 + aq) ^ swz) << 3;
            #pragma unroll
            for (int nt = 0; nt < 4; ++nt) {
                bf8 bb = ld_bf8(&ks[cur][(nt * 16 + coll) * 128 + slot8]);
                sacc[nt] = __builtin_amdgcn_mfma_f32_16x16x32_bf16(qf[kk], bb, sacc[nt], 0, 0, 0);
            }
        }

        #pragma unroll
        for (int r = 0; r < 4; ++r) {
            float s0 = sacc[0][r], s1 = sacc[1][r], s2 = sacc[2][r], s3 = sacc[3][r];
            if (masked) {
                int qi = qbase + w * 16 + aq * 4 + r;
                int ki = sbase + coll;
                s0 = (ki      > qi) ? -1e30f : s0;
                s1 = (ki + 16 > qi) ? -1e30f : s1;
                s2 = (ki + 32 > qi) ? -1e30f : s2;
                s3 = (ki + 48 > qi) ? -1e30f : s3;
            }
            float p0 = __builtin_amdgcn_exp2f(s0);
            float p1 = __builtin_amdgcn_exp2f(s1);
            float p2 = __builtin_amdgcn_exp2f(s2);
            float p3 = __builtin_amdgcn_exp2f(s3);
            const int prow = (aq * 4 + r) * 72;
            psw[prow + coll]      = __builtin_bit_cast(unsigned short, (__bf16)p0);
            psw[prow + 16 + coll] = __builtin_bit_cast(unsigned short, (__bf16)p1);
            psw[prow + 32 + coll] = __builtin_bit_cast(unsigned short, (__bf16)p2);
            psw[prow + 48 + coll] = __builtin_bit_cast(unsigned short, (__bf16)p3);
        }

        #pragma unroll
        for (int kk = 0; kk < 2; ++kk) {
            bf8 a = ld_bf8(&psw[coll * 72 + kk * 32 + aq * 8]);
            accL = __builtin_amdgcn_mfma_f32_16x16x32_bf16(a, ones, accL, 0, 0, 0);
            const int slot8 = ((kk * 4 + aq) ^ swz) << 3;
            #pragma unroll
            for (int nt = 0; nt < 8; ++nt) {
                bf8 bb = ld_bf8(&vs[cur][(nt * 16 + coll) * 64 + slot8]);
                accO[nt] = __builtin_amdgcn_mfma_f32_16x16x32_bf16(a, bb, accO[nt], 0, 0, 0);
            }
        }

        barrier_raw();
        cur ^= 1;
    }

    unsigned short* op = partO + (size_t)slot * (64 * 128);
    #pragma unroll
    for (int r = 0; r < 4; ++r) {
        int row = w * 16 + aq * 4 + r;
        #pragma unroll
        for (int nt = 0; nt < 8; ++nt) {
            __bf16 ob = (__bf16)accO[nt][r];
            op[row * 128 + nt * 16 + coll] = __builtin_bit_cast(unsigned short, ob);
        }
        if (coll == 0) partL[slot * 64 + row] = accL[r];
    }
}

// ---------------------------------------------------------------------------
// Kernel 2b: merge partials. Grid 256 = (b,qt).
// ---------------------------------------------------------------------------
__global__ __launch_bounds__(256) void attn_merge(
    const unsigned short* __restrict__ partO, const float* __restrict__ partL,
    float* __restrict__ out)
{
    const int bq = blockIdx.x;
    const int b = bq >> 6, qt = bq & 63;
    const int g = qt >> 3;
    const int nc = g + 1;
    const int slotbase = b * 288 + 4 * g * (g + 1) + (qt & 7) * (g + 1);
    const int row = threadIdx.x >> 2;
    const int cg = (threadIdx.x & 3) * 32;

    float acc[32];
    #pragma unroll
    for (int e = 0; e < 32; ++e) acc[e] = 0.f;
    float L = 0.f;
    for (int c = 0; c < nc; ++c) {
        const int slot = slotbase + c;
        L += partL[slot * 64 + row];
        const unsigned short* op = partO + (size_t)slot * (64 * 128) + row * 128 + cg;
        #pragma unroll
        for (int k = 0; k < 4; ++k) {
            u16x8 t = *(const u16x8*)(op + k * 8);
            #pragma unroll
            for (int e = 0; e < 8; ++e) acc[k * 8 + e] += bf2f(t[e]);
        }
    }
    float inv = 1.f / L;
    float* dst = out + ((size_t)(b * T_ + qt * 64 + row)) * HD_ + cg;
    #pragma unroll
    for (int k = 0; k < 8; ++k) {
        float4 o;
        o.x = acc[k * 4 + 0] * inv; o.y = acc[k * 4 + 1] * inv;
        o.z = acc[k * 4 + 2] * inv; o.w = acc[k * 4 + 3] * inv;
        *(float4*)(dst + k * 4) = o;
    }
}

extern "C" void kernel_launch(void* const* d_in, const int* in_sizes, int n_in,
                              void* d_out, int out_size, void* d_ws, size_t ws_size,
                              hipStream_t stream) {
    const float* x    = (const float*)d_in[0];
    const float* Wq   = (const float*)d_in[1];
    const float* Wk   = (const float*)d_in[2];
    const float* Wv   = (const float*)d_in[3];
    const float* cosp = (const float*)d_in[4];
    const float* sinp = (const float*)d_in[5];
    float* out = (float*)d_out;

    unsigned short* qws = (unsigned short*)d_ws;              // 4 MB
    unsigned short* kws = qws + (size_t)M_ * HD_;             // 4 MB
    unsigned short* vws = kws + (size_t)M_ * HD_;             // (B,128,T) 4 MB
    unsigned short* wbf = vws + (size_t)M_ * HD_;             // 1.5 MB
    unsigned short* partO = wbf + (size_t)3 * HD_ * C_;       // 1152*8192 u16 = 18.9 MB
    float* partL = (float*)(partO + (size_t)1152 * 64 * 128); // 1152*64 f32

    wconv<<<dim3(384), dim3(256), 0, stream>>>(Wq, Wk, Wv, wbf);
    qkv_gemm<<<dim3(768), dim3(256), 0, stream>>>(x, wbf, cosp, sinp, qws, kws, vws);
    attn_part<<<dim3(1152), dim3(256), 0, stream>>>(qws, kws, vws, partO, partL);
    attn_merge<<<dim3(256), dim3(256), 0, stream>>>(partO, partL, out);
}